// Round 1
// baseline (7251.104 us; speedup 1.0000x reference)
//
#include <hip/hip_runtime.h>
#include <math.h>

namespace {
constexpr int kH = 256;
constexpr int kL = 4;
constexpr int kAtomDim = 100;
constexpr int kTDim = 128;
constexpr int kNF = 10;
constexpr int kB = 128;
constexpr int kNN = 32;
constexpr int kGS = 8;
constexpr int kN = kB * kNN;       // 4096
constexpr int kE = kB * kNN * kNN; // 131072
constexpr int kFeat = 69;          // 6 lat + 60 dis + 3 l_f
constexpr int kDinE = 581;
constexpr float kTwoPi = 6.28318530717958647692f;

__device__ __forceinline__ float silu(float x) { return x / (1.0f + expf(-x)); }

// ---------------- per-graph lattice: ltl = expm(S)^T expm(S) ----------------
__global__ void lattice_kernel(const float* __restrict__ lattices,
                               const float* __restrict__ k_mean,
                               const float* __restrict__ k_std,
                               const float* __restrict__ k_mask,
                               const float* __restrict__ k_bias,
                               float* __restrict__ ltl) {
    int b = threadIdx.x;
    if (b >= kB) return;
    double y[6];
    for (int k = 0; k < 6; ++k) {
        double v = (double)lattices[b * 6 + k] * (double)k_std[k] + (double)k_mean[k];
        y[k] = v * (double)k_mask[k] + (double)k_bias[k];
    }
    double A[9] = { y[0], y[3], y[4],
                    y[3], y[1], y[5],
                    y[4], y[5], y[2] };
    double nrm = 0.0;
    for (int i = 0; i < 3; ++i) {
        double r = fabs(A[i*3+0]) + fabs(A[i*3+1]) + fabs(A[i*3+2]);
        nrm = fmax(nrm, r);
    }
    int s = 0;
    while (nrm > 0.25 && s < 40) { nrm *= 0.5; s++; }
    double sc = 1.0;
    for (int i = 0; i < s; ++i) sc *= 0.5;
    for (int i = 0; i < 9; ++i) A[i] *= sc;
    double T[9]    = {1,0,0, 0,1,0, 0,0,1};
    double term[9] = {1,0,0, 0,1,0, 0,0,1};
    for (int it = 1; it <= 18; ++it) {
        double nt[9];
        double inv = 1.0 / (double)it;
        for (int i = 0; i < 3; ++i)
            for (int j = 0; j < 3; ++j) {
                double acc = 0.0;
                for (int k = 0; k < 3; ++k) acc += term[i*3+k] * A[k*3+j];
                nt[i*3+j] = acc * inv;
            }
        for (int i = 0; i < 9; ++i) { term[i] = nt[i]; T[i] += nt[i]; }
    }
    for (int q = 0; q < s; ++q) {
        double nt[9];
        for (int i = 0; i < 3; ++i)
            for (int j = 0; j < 3; ++j) {
                double acc = 0.0;
                for (int k = 0; k < 3; ++k) acc += T[i*3+k] * T[k*3+j];
                nt[i*3+j] = acc;
            }
        for (int i = 0; i < 9; ++i) T[i] = nt[i];
    }
    // ltl[i][k] = sum_j T[j][i] * T[j][k]
    for (int i = 0; i < 3; ++i)
        for (int k = 0; k < 3; ++k) {
            double acc = 0.0;
            for (int j = 0; j < 3; ++j) acc += T[j*3+i] * T[j*3+k];
            ltl[b*9 + i*3 + k] = (float)acc;
        }
}

// ---------------- per-edge geometric features [lat(6)|sin(30)|cos(30)|l_f(3)] ----
__global__ void feats_kernel(const float* __restrict__ frac,
                             const float* __restrict__ lattices,
                             const float* __restrict__ ltl,
                             float* __restrict__ feats) {
    int e = blockIdx.x * blockDim.x + threadIdx.x;
    if (e >= kE) return;
    int g = e >> 10;
    int src = (g << 5) + ((e >> 5) & 31);
    int dst = (g << 5) + (e & 31);
    float d[3];
    #pragma unroll
    for (int c = 0; c < 3; ++c) {
        float z = kTwoPi * (frac[dst*3 + c] - frac[src*3 + c]);
        d[c] = atan2f(sinf(z), cosf(z)) * (1.0f / kTwoPi);
    }
    float* f = feats + (size_t)e * kFeat;
    #pragma unroll
    for (int k = 0; k < 6; ++k) f[k] = lattices[g*6 + k];
    #pragma unroll
    for (int c = 0; c < 3; ++c)
        for (int fr = 0; fr < kNF; ++fr) {
            float v = d[c] * (kTwoPi * (float)fr);
            f[6  + c*kNF + fr] = sinf(v);
            f[36 + c*kNF + fr] = cosf(v);
        }
    float v0 = ltl[g*9+0]*d[0] + ltl[g*9+1]*d[1] + ltl[g*9+2]*d[2];
    float v1 = ltl[g*9+3]*d[0] + ltl[g*9+4]*d[1] + ltl[g*9+5]*d[2];
    float v2 = ltl[g*9+6]*d[0] + ltl[g*9+7]*d[1] + ltl[g*9+8]*d[2];
    float nr = sqrtf(v0*v0 + v1*v1 + v2*v2) + 1e-6f;
    f[66] = v0/nr; f[67] = v1/nr; f[68] = v2/nr;
}

// ---------------- node embedding + time embedding + latent proj ----------------
__global__ void embed_kernel(const float* __restrict__ atom_types,
                             const float* __restrict__ t,
                             const float* __restrict__ emb_w, const float* __restrict__ emb_b,
                             const float* __restrict__ latent_w, const float* __restrict__ latent_b,
                             float* __restrict__ h) {
    int n = blockIdx.x;
    int tid = threadIdx.x;
    int g = n >> 5;
    __shared__ float at[kAtomDim];
    __shared__ float te[kTDim];
    __shared__ float h0[kH];
    if (tid < kAtomDim) at[tid] = atom_types[(size_t)n*kAtomDim + tid];
    if (tid < 64) {
        float tf = expf(-logf(10000.0f) * (float)tid / 64.0f);
        float ta = t[g] * tf;
        te[tid]      = cosf(ta);   // cos first
        te[tid + 64] = sinf(ta);
    }
    __syncthreads();
    int c = tid;
    float acc = emb_b[c];
    const float* wr = emb_w + (size_t)c*kAtomDim;
    #pragma unroll 4
    for (int k = 0; k < kAtomDim; ++k) acc += at[k]*wr[k];
    h0[c] = acc;
    __syncthreads();
    float acc2 = latent_b[c];
    const float* lr = latent_w + (size_t)c*(kH + kTDim);
    #pragma unroll 4
    for (int k = 0; k < kH; ++k) acc2 += h0[k]*lr[k];
    #pragma unroll 4
    for (int k = 0; k < kTDim; ++k) acc2 += te[k]*lr[kH + k];
    h[(size_t)n*kH + c] = acc2;
}

// ---------------- per-node S = h@W1a^T, D = h@W1b^T ----------------
__global__ void sd_kernel(const float* __restrict__ h,
                          const float* __restrict__ w1, // [256][581] layer base
                          float* __restrict__ S, float* __restrict__ D) {
    int n = blockIdx.x;
    int c = threadIdx.x;
    __shared__ float hn[kH];
    hn[c] = h[(size_t)n*kH + c];
    __syncthreads();
    const float* wr = w1 + (size_t)c*kDinE;
    float s = 0.f, dacc = 0.f;
    #pragma unroll 4
    for (int k = 0; k < kH; ++k) {
        float hv = hn[k];
        s    += hv * wr[k];
        dacc += hv * wr[kH + k];
    }
    S[(size_t)n*kH + c] = s;
    D[(size_t)n*kH + c] = dacc;
}

// ---------------- fused edge MLP (ef1 = silu(S+D+F+b1); ef2 = silu(ef1@W2^T+b2); agg) ---
__global__ __launch_bounds__(256) void edge_kernel(
        const float* __restrict__ S, const float* __restrict__ D,
        const float* __restrict__ feats,
        const float* __restrict__ w1,  // layer base; only cols [512,581) used
        const float* __restrict__ b1,
        const float* __restrict__ w2, const float* __restrict__ b2,
        float* __restrict__ agg) {
    int n = blockIdx.x;
    int tid = threadIdx.x;
    int gbase = (n >> 5) << 5;
    size_t ebase = (size_t)n * kNN;
    __shared__ float sS[kH];
    __shared__ float ef1[kNN][kH];   // starts as D[dst], becomes silu(ein@W1)
    __shared__ float fT[kFeat][kNN];
    __shared__ float red[4][kH];

    sS[tid] = S[(size_t)n*kH + tid] + b1[tid];
    #pragma unroll
    for (int e = 0; e < kNN; ++e)
        ef1[e][tid] = D[(size_t)(gbase + e)*kH + tid];
    for (int idx = tid; idx < kNN*kFeat; idx += 256) {
        int e = idx / kFeat, k = idx - e*kFeat;
        fT[k][e] = feats[(ebase + e)*kFeat + k];
    }
    __syncthreads();

    { // ef1[e][c] = silu(S[src][c] + D[dst_e][c] + F[e][c] + b1[c]), c = tid
        int c = tid;
        float acc[kNN];
        #pragma unroll
        for (int e = 0; e < kNN; ++e) acc[e] = 0.f;
        const float* wr = w1 + (size_t)c*kDinE + 512;
        for (int k = 0; k < kFeat; ++k) {
            float wv = wr[k];
            const float4* frow = (const float4*)&fT[k][0];
            #pragma unroll
            for (int e4 = 0; e4 < kNN/4; ++e4) {
                float4 f4 = frow[e4];
                acc[e4*4+0] += wv * f4.x;
                acc[e4*4+1] += wv * f4.y;
                acc[e4*4+2] += wv * f4.z;
                acc[e4*4+3] += wv * f4.w;
            }
        }
        float sv = sS[c];
        #pragma unroll
        for (int e = 0; e < kNN; ++e) {
            float x = sv + ef1[e][c] + acc[e];
            ef1[e][c] = silu(x);
        }
    }
    __syncthreads();

    { // GEMM2: out2[e][c] = silu(ef1[e][:]@W2[c][:] + b2[c]); partial agg per edge-group
        int eg = tid >> 6;   // 0..3 -> edges 8eg..8eg+7
        int cg = tid & 63;   // cols 4cg..4cg+3
        float acc[8][4];
        #pragma unroll
        for (int i = 0; i < 8; ++i)
            #pragma unroll
            for (int j = 0; j < 4; ++j) acc[i][j] = 0.f;
        const float* w2r0 = w2 + (size_t)(cg*4 + 0)*kH;
        const float* w2r1 = w2 + (size_t)(cg*4 + 1)*kH;
        const float* w2r2 = w2 + (size_t)(cg*4 + 2)*kH;
        const float* w2r3 = w2 + (size_t)(cg*4 + 3)*kH;
        for (int k = 0; k < kH; k += 4) {
            float4 wv0 = *(const float4*)&w2r0[k];
            float4 wv1 = *(const float4*)&w2r1[k];
            float4 wv2 = *(const float4*)&w2r2[k];
            float4 wv3 = *(const float4*)&w2r3[k];
            #pragma unroll
            for (int i = 0; i < 8; ++i) {
                float4 ev = *(const float4*)&ef1[eg*8 + i][k];
                acc[i][0] += ev.x*wv0.x + ev.y*wv0.y + ev.z*wv0.z + ev.w*wv0.w;
                acc[i][1] += ev.x*wv1.x + ev.y*wv1.y + ev.z*wv1.z + ev.w*wv1.w;
                acc[i][2] += ev.x*wv2.x + ev.y*wv2.y + ev.z*wv2.z + ev.w*wv2.w;
                acc[i][3] += ev.x*wv3.x + ev.y*wv3.y + ev.z*wv3.z + ev.w*wv3.w;
            }
        }
        #pragma unroll
        for (int j = 0; j < 4; ++j) {
            int c = cg*4 + j;
            float bb = b2[c];
            float p = 0.f;
            #pragma unroll
            for (int i = 0; i < 8; ++i) p += silu(acc[i][j] + bb);
            red[eg][c] = p;
        }
    }
    __syncthreads();
    {
        int c = tid;
        float a = (red[0][c] + red[1][c] + red[2][c] + red[3][c]) * (1.0f/32.0f);
        agg[(size_t)n*kH + c] = a;
    }
}

// ---------------- node update: h += silu(silu([h|agg]@Nw1^T+b)@Nw2^T+b) ----------------
__global__ void node_kernel(float* __restrict__ h,
                            const float* __restrict__ agg,
                            const float* __restrict__ nw1, const float* __restrict__ nb1,
                            const float* __restrict__ nw2, const float* __restrict__ nb2) {
    int n = blockIdx.x;
    int c = threadIdx.x;
    __shared__ float cat[2*kH];
    __shared__ float t1[kH];
    cat[c]      = h[(size_t)n*kH + c];
    cat[kH + c] = agg[(size_t)n*kH + c];
    __syncthreads();
    const float* wr = nw1 + (size_t)c*(2*kH);
    float acc = nb1[c];
    for (int k = 0; k < 2*kH; k += 4) {
        float4 cv = *(const float4*)&cat[k];
        float4 wv = *(const float4*)&wr[k];
        acc += cv.x*wv.x + cv.y*wv.y + cv.z*wv.z + cv.w*wv.w;
    }
    t1[c] = silu(acc);
    __syncthreads();
    const float* wr2 = nw2 + (size_t)c*kH;
    float acc2 = nb2[c];
    for (int k = 0; k < kH; k += 4) {
        float4 cv = *(const float4*)&t1[k];
        float4 wv = *(const float4*)&wr2[k];
        acc2 += cv.x*wv.x + cv.y*wv.y + cv.z*wv.z + cv.w*wv.w;
    }
    h[(size_t)n*kH + c] += silu(acc2);
}

// ---------------- heads: coord + equivariant group-average ----------------
__global__ void coord_equiv_kernel(const float* __restrict__ h,
                                   const float* __restrict__ coord_w,
                                   const float* __restrict__ G,
                                   const int* __restrict__ invp,
                                   float* __restrict__ out_x) {
    int b = blockIdx.x;
    int tid = threadIdx.x; // 128
    __shared__ float cd[kNN][4];
    if (tid < kNN*3) {
        int nl = tid / 3, j = tid - nl*3;
        const float* hr = h + (size_t)(b*kNN + nl)*kH;
        const float* wr = coord_w + (size_t)j*kH;
        float acc = 0.f;
        #pragma unroll 4
        for (int k = 0; k < kH; ++k) acc += hr[k]*wr[k];
        cd[nl][j] = acc;
    }
    __syncthreads();
    if (tid < kNN*3) {
        int nl = tid / 3, j = tid - nl*3;
        float acc = 0.f;
        for (int g = 0; g < kGS; ++g) {
            int bg = b*kGS + g;
            int p = invp[bg*kNN + nl];
            const float* Gr = G + (size_t)bg*16 + j*4;
            acc += cd[p][0]*Gr[0] + cd[p][1]*Gr[1] + cd[p][2]*Gr[2] + Gr[3];
        }
        out_x[(size_t)(b*kNN + nl)*3 + j] = acc * (1.0f/kGS);
    }
}

__global__ void graphfeat_kernel(const float* __restrict__ h,
                                 const float* __restrict__ lattice_w,
                                 float* __restrict__ out_lat) {
    int g = blockIdx.x;
    int c = threadIdx.x;
    __shared__ float gf[kH];
    float s = 0.f;
    for (int nl = 0; nl < kNN; ++nl) s += h[(size_t)(g*kNN + nl)*kH + c];
    gf[c] = s * (1.0f/kNN);
    __syncthreads();
    if (c < 6) {
        const float* wr = lattice_w + (size_t)c*kH;
        float acc = 0.f;
        #pragma unroll 4
        for (int k = 0; k < kH; ++k) acc += gf[k]*wr[k];
        out_lat[g*6 + c] = acc;
    }
}

} // namespace

extern "C" void kernel_launch(void* const* d_in, const int* in_sizes, int n_in,
                              void* d_out, int out_size, void* d_ws, size_t ws_size,
                              hipStream_t stream) {
    (void)in_sizes; (void)n_in; (void)out_size; (void)ws_size;
    const float* t         = (const float*)d_in[0];
    const float* atom      = (const float*)d_in[1];
    const float* frac      = (const float*)d_in[2];
    const float* lattices  = (const float*)d_in[3];
    const float* G         = (const float*)d_in[4];
    const float* k_mean    = (const float*)d_in[5];
    const float* k_std     = (const float*)d_in[6];
    const float* k_mask    = (const float*)d_in[7];
    const float* k_bias    = (const float*)d_in[8];
    const float* emb_w     = (const float*)d_in[9];
    const float* emb_b     = (const float*)d_in[10];
    const float* latent_w  = (const float*)d_in[11];
    const float* latent_b  = (const float*)d_in[12];
    const float* edge_w1   = (const float*)d_in[13];
    const float* edge_b1   = (const float*)d_in[14];
    const float* edge_w2   = (const float*)d_in[15];
    const float* edge_b2   = (const float*)d_in[16];
    const float* node_w1   = (const float*)d_in[17];
    const float* node_b1   = (const float*)d_in[18];
    const float* node_w2   = (const float*)d_in[19];
    const float* node_b2   = (const float*)d_in[20];
    const float* coord_w   = (const float*)d_in[21];
    const float* lattice_w = (const float*)d_in[22];
    const int*   invp      = (const int*)d_in[25];

    float* out_x   = (float*)d_out;            // [4096,3]
    float* out_lat = (float*)d_out + kN*3;     // [128,6]

    float* ws    = (float*)d_ws;
    float* ltl   = ws;                 // 128*9
    float* h     = ws + 2048;          // 4096*256
    float* Sbuf  = h    + (size_t)kN*kH;
    float* Dbuf  = Sbuf + (size_t)kN*kH;
    float* aggb  = Dbuf + (size_t)kN*kH;
    float* feats = aggb + (size_t)kN*kH;  // E*69

    lattice_kernel<<<1, 128, 0, stream>>>(lattices, k_mean, k_std, k_mask, k_bias, ltl);
    feats_kernel<<<kE/256, 256, 0, stream>>>(frac, lattices, ltl, feats);
    embed_kernel<<<kN, 256, 0, stream>>>(atom, t, emb_w, emb_b, latent_w, latent_b, h);
    for (int l = 0; l < kL; ++l) {
        const float* w1 = edge_w1 + (size_t)l*kH*kDinE;
        const float* b1 = edge_b1 + (size_t)l*kH;
        const float* w2 = edge_w2 + (size_t)l*kH*kH;
        const float* b2 = edge_b2 + (size_t)l*kH;
        sd_kernel<<<kN, 256, 0, stream>>>(h, w1, Sbuf, Dbuf);
        edge_kernel<<<kN, 256, 0, stream>>>(Sbuf, Dbuf, feats, w1, b1, w2, b2, aggb);
        node_kernel<<<kN, 256, 0, stream>>>(h, aggb,
            node_w1 + (size_t)l*kH*2*kH, node_b1 + (size_t)l*kH,
            node_w2 + (size_t)l*kH*kH,   node_b2 + (size_t)l*kH);
    }
    coord_equiv_kernel<<<kB, 128, 0, stream>>>(h, coord_w, G, invp, out_x);
    graphfeat_kernel<<<kB, 256, 0, stream>>>(h, lattice_w, out_lat);
}

// Round 3
// 1279.251 us; speedup vs baseline: 5.6682x; 5.6682x over previous
//
#include <hip/hip_runtime.h>
#include <math.h>

namespace {
constexpr int kH = 256;
constexpr int kL = 4;
constexpr int kAtomDim = 100;
constexpr int kB = 128;
constexpr int kNN = 32;
constexpr int kGS = 8;
constexpr int kN = kB * kNN;       // 4096
constexpr int kE = kB * kNN * kNN; // 131072
constexpr int kDinE = 581;
constexpr int kKF = 96;            // padded feature K (69 -> 96)
constexpr float kTwoPi = 6.28318530717958647692f;

typedef __bf16 bf16x8 __attribute__((ext_vector_type(8)));
typedef float  f32x4  __attribute__((ext_vector_type(4)));

__device__ __forceinline__ float silu(float x) { return x / (1.0f + expf(-x)); }

// ---------------- per-graph lattice: ltl = expm(S)^T expm(S) ----------------
__global__ void lattice_kernel(const float* __restrict__ lattices,
                               const float* __restrict__ k_mean,
                               const float* __restrict__ k_std,
                               const float* __restrict__ k_mask,
                               const float* __restrict__ k_bias,
                               float* __restrict__ ltl) {
    int b = threadIdx.x;
    if (b >= kB) return;
    double y[6];
    for (int k = 0; k < 6; ++k) {
        double v = (double)lattices[b * 6 + k] * (double)k_std[k] + (double)k_mean[k];
        y[k] = v * (double)k_mask[k] + (double)k_bias[k];
    }
    double A[9] = { y[0], y[3], y[4],
                    y[3], y[1], y[5],
                    y[4], y[5], y[2] };
    double nrm = 0.0;
    for (int i = 0; i < 3; ++i) {
        double r = fabs(A[i*3+0]) + fabs(A[i*3+1]) + fabs(A[i*3+2]);
        nrm = fmax(nrm, r);
    }
    int s = 0;
    while (nrm > 0.25 && s < 40) { nrm *= 0.5; s++; }
    double sc = 1.0;
    for (int i = 0; i < s; ++i) sc *= 0.5;
    for (int i = 0; i < 9; ++i) A[i] *= sc;
    double T[9]    = {1,0,0, 0,1,0, 0,0,1};
    double term[9] = {1,0,0, 0,1,0, 0,0,1};
    for (int it = 1; it <= 18; ++it) {
        double nt[9];
        double inv = 1.0 / (double)it;
        for (int i = 0; i < 3; ++i)
            for (int j = 0; j < 3; ++j) {
                double acc = 0.0;
                for (int k = 0; k < 3; ++k) acc += term[i*3+k] * A[k*3+j];
                nt[i*3+j] = acc * inv;
            }
        for (int i = 0; i < 9; ++i) { term[i] = nt[i]; T[i] += nt[i]; }
    }
    for (int q = 0; q < s; ++q) {
        double nt[9];
        for (int i = 0; i < 3; ++i)
            for (int j = 0; j < 3; ++j) {
                double acc = 0.0;
                for (int k = 0; k < 3; ++k) acc += T[i*3+k] * T[k*3+j];
                nt[i*3+j] = acc;
            }
        for (int i = 0; i < 9; ++i) T[i] = nt[i];
    }
    for (int i = 0; i < 3; ++i)
        for (int k = 0; k < 3; ++k) {
            double acc = 0.0;
            for (int j = 0; j < 3; ++j) acc += T[j*3+i] * T[j*3+k];
            ltl[b*9 + i*3 + k] = (float)acc;
        }
}

// ------- per-edge geometric features, bf16, padded to 96 cols with zeros -------
__global__ void feats_bf_kernel(const float* __restrict__ frac,
                                const float* __restrict__ lattices,
                                const float* __restrict__ ltl,
                                __bf16* __restrict__ out) {
    int e = blockIdx.x * blockDim.x + threadIdx.x;
    if (e >= kE) return;
    int g = e >> 10;
    int src = (g << 5) + ((e >> 5) & 31);
    int dst = (g << 5) + (e & 31);
    float d[3];
    #pragma unroll
    for (int c = 0; c < 3; ++c) {
        float z = kTwoPi * (frac[dst*3 + c] - frac[src*3 + c]);
        d[c] = atan2f(sinf(z), cosf(z)) * (1.0f / kTwoPi);
    }
    __bf16* f = out + (size_t)e * kKF;
    #pragma unroll
    for (int k = 0; k < 6; ++k) f[k] = (__bf16)lattices[g*6 + k];
    #pragma unroll
    for (int c = 0; c < 3; ++c)
        #pragma unroll
        for (int fr = 0; fr < 10; ++fr) {
            float v = d[c] * (kTwoPi * (float)fr);
            f[6  + c*10 + fr] = (__bf16)sinf(v);
            f[36 + c*10 + fr] = (__bf16)cosf(v);
        }
    float v0 = ltl[g*9+0]*d[0] + ltl[g*9+1]*d[1] + ltl[g*9+2]*d[2];
    float v1 = ltl[g*9+3]*d[0] + ltl[g*9+4]*d[1] + ltl[g*9+5]*d[2];
    float v2 = ltl[g*9+6]*d[0] + ltl[g*9+7]*d[1] + ltl[g*9+8]*d[2];
    float nr = sqrtf(v0*v0 + v1*v1 + v2*v2) + 1e-6f;
    f[66] = (__bf16)(v0/nr); f[67] = (__bf16)(v1/nr); f[68] = (__bf16)(v2/nr);
    #pragma unroll
    for (int k = 69; k < kKF; ++k) f[k] = (__bf16)0.0f;
}

// ---------------- weight conversion kernels ----------------
__global__ void conv_f2b(const float* __restrict__ s, __bf16* __restrict__ d, int n) {
    int i = blockIdx.x * 256 + threadIdx.x;
    if (i < n) d[i] = (__bf16)s[i];
}
// w1ab: [L][512][256]: rows 0..255 = w1[c][0:256] (S part), rows 256..511 = w1[c][256:512] (D part)
__global__ void conv_w1ab(const float* __restrict__ w1, __bf16* __restrict__ dst) {
    int i = blockIdx.x * 256 + threadIdx.x;   // 4*512*256
    int l = i >> 17;
    int rem = i & 131071;
    int r = rem >> 8;
    int k = rem & 255;
    float v = (r < 256) ? w1[((size_t)(l*256 + r))*kDinE + k]
                        : w1[((size_t)(l*256 + (r-256)))*kDinE + 256 + k];
    dst[i] = (__bf16)v;
}
// w1c: [L][256][96]: w1[n][512+k] for k<69 else 0
__global__ void conv_w1c(const float* __restrict__ w1, __bf16* __restrict__ dst) {
    int i = blockIdx.x * 256 + threadIdx.x;   // 4*256*96
    int l = i / (256*kKF);
    int rem = i - l*256*kKF;
    int n = rem / kKF;
    int k = rem - n*kKF;
    float v = (k < 69) ? w1[((size_t)(l*256 + n))*kDinE + 512 + k] : 0.0f;
    dst[i] = (__bf16)v;
}

// ---------------- node embedding + time embedding + latent proj ----------------
__global__ void embed_kernel(const float* __restrict__ atom_types,
                             const float* __restrict__ t,
                             const float* __restrict__ emb_w, const float* __restrict__ emb_b,
                             const float* __restrict__ latent_w, const float* __restrict__ latent_b,
                             float* __restrict__ h, __bf16* __restrict__ hcat) {
    int n = blockIdx.x;
    int tid = threadIdx.x;
    int g = n >> 5;
    __shared__ float at[kAtomDim];
    __shared__ float te[128];
    __shared__ float h0[kH];
    if (tid < kAtomDim) at[tid] = atom_types[(size_t)n*kAtomDim + tid];
    if (tid < 64) {
        float tf = expf(-logf(10000.0f) * (float)tid / 64.0f);
        float ta = t[g] * tf;
        te[tid]      = cosf(ta);   // cos first
        te[tid + 64] = sinf(ta);
    }
    __syncthreads();
    int c = tid;
    float acc = emb_b[c];
    const float* wr = emb_w + (size_t)c*kAtomDim;
    #pragma unroll 4
    for (int k = 0; k < kAtomDim; ++k) acc += at[k]*wr[k];
    h0[c] = acc;
    __syncthreads();
    float acc2 = latent_b[c];
    const float* lr = latent_w + (size_t)c*(kH + 128);
    #pragma unroll 4
    for (int k = 0; k < kH; ++k) acc2 += h0[k]*lr[k];
    #pragma unroll 4
    for (int k = 0; k < 128; ++k) acc2 += te[k]*lr[kH + k];
    h[(size_t)n*kH + c] = acc2;
    hcat[(size_t)n*512 + c] = (__bf16)acc2;
}

// ---------------- generic 128x128-tile bf16 GEMM: C = A[M][lda] @ W[N][ldw]^T ----------------
// EPI 0: Sb/D split (N=512): n<256 -> out0 = acc+bias, else out1 = acc
// EPI 1: outbf = bf16(acc)
// EPI 2: outbf = bf16(silu(acc+bias))
// EPI 3: h += silu(acc+bias); write h fp32 + hcat bf16
template<int K, int EPI>
__global__ __launch_bounds__(256) void gemm_bf16(
        const __bf16* __restrict__ A, int lda,
        const __bf16* __restrict__ W, int ldw,
        const float* __restrict__ bias,
        float* __restrict__ out0, float* __restrict__ out1,
        __bf16* __restrict__ outbf,
        float* __restrict__ hmaster, __bf16* __restrict__ hcat) {
    constexpr int NC = K / 32;
    __shared__ __bf16 As[2][128*40];
    __shared__ __bf16 Bs[2][128*40];
    int tid = threadIdx.x;
    int lane = tid & 63;
    int wid = tid >> 6;
    int wm = wid >> 1, wn = wid & 1;
    int r16 = lane & 15, g4 = lane >> 4;
    int mbase = blockIdx.x * 128;
    int nbase = blockIdx.y * 128;
    int srow = tid >> 1, shalf = tid & 1;
    const __bf16* agp = A + (size_t)(mbase + srow)*lda + shalf*16;
    const __bf16* wgp = W + (size_t)(nbase + srow)*ldw + shalf*16;
    int woff = srow*40 + shalf*16;

    f32x4 acc[4][4] = {};
    uint4 ra0, ra1, rb0, rb1;
    ra0 = *(const uint4*)(agp);     ra1 = *(const uint4*)(agp + 8);
    rb0 = *(const uint4*)(wgp);     rb1 = *(const uint4*)(wgp + 8);
    *(uint4*)&As[0][woff]     = ra0;  *(uint4*)&As[0][woff + 8] = ra1;
    *(uint4*)&Bs[0][woff]     = rb0;  *(uint4*)&Bs[0][woff + 8] = rb1;
    __syncthreads();
    for (int c = 0; c < NC; ++c) {
        int cur = c & 1;
        if (c + 1 < NC) {
            ra0 = *(const uint4*)(agp + (c+1)*32);  ra1 = *(const uint4*)(agp + (c+1)*32 + 8);
            rb0 = *(const uint4*)(wgp + (c+1)*32);  rb1 = *(const uint4*)(wgp + (c+1)*32 + 8);
        }
        bf16x8 af[4], bfg[4];
        #pragma unroll
        for (int mt = 0; mt < 4; ++mt)
            af[mt] = *(const bf16x8*)&As[cur][(wm*64 + mt*16 + r16)*40 + g4*8];
        #pragma unroll
        for (int nt = 0; nt < 4; ++nt)
            bfg[nt] = *(const bf16x8*)&Bs[cur][(wn*64 + nt*16 + r16)*40 + g4*8];
        #pragma unroll
        for (int mt = 0; mt < 4; ++mt)
            #pragma unroll
            for (int nt = 0; nt < 4; ++nt)
                acc[mt][nt] = __builtin_amdgcn_mfma_f32_16x16x32_bf16(af[mt], bfg[nt], acc[mt][nt], 0, 0, 0);
        if (c + 1 < NC) {
            int nxt = cur ^ 1;
            *(uint4*)&As[nxt][woff]     = ra0;  *(uint4*)&As[nxt][woff + 8] = ra1;
            *(uint4*)&Bs[nxt][woff]     = rb0;  *(uint4*)&Bs[nxt][woff + 8] = rb1;
        }
        __syncthreads();
    }
    #pragma unroll
    for (int mt = 0; mt < 4; ++mt)
        #pragma unroll
        for (int nt = 0; nt < 4; ++nt) {
            int n = nbase + wn*64 + nt*16 + r16;
            #pragma unroll
            for (int r = 0; r < 4; ++r) {
                int m = mbase + wm*64 + mt*16 + g4*4 + r;
                float v = acc[mt][nt][r];
                if (EPI == 0) {
                    if (n < 256) out0[(size_t)m*256 + n] = v + bias[n];
                    else         out1[(size_t)m*256 + (n - 256)] = v;
                } else if (EPI == 1) {
                    outbf[(size_t)m*256 + n] = (__bf16)v;
                } else if (EPI == 2) {
                    outbf[(size_t)m*256 + n] = (__bf16)silu(v + bias[n]);
                } else {
                    float hv = hmaster[(size_t)m*256 + n] + silu(v + bias[n]);
                    hmaster[(size_t)m*256 + n] = hv;
                    hcat[(size_t)m*512 + n] = (__bf16)hv;
                }
            }
        }
}

// ---- helper: 4+4 fp32 + 8 bf16 feature -> silu -> bf16x8 ----
__device__ __forceinline__ bf16x8 packA8(float4 sa, float4 sb2, float4 da, float4 db, bf16x8 f) {
    bf16x8 o;
    o[0] = (__bf16)silu(sa.x  + da.x + (float)f[0]);
    o[1] = (__bf16)silu(sa.y  + da.y + (float)f[1]);
    o[2] = (__bf16)silu(sa.z  + da.z + (float)f[2]);
    o[3] = (__bf16)silu(sa.w  + da.w + (float)f[3]);
    o[4] = (__bf16)silu(sb2.x + db.x + (float)f[4]);
    o[5] = (__bf16)silu(sb2.y + db.y + (float)f[5]);
    o[6] = (__bf16)silu(sb2.z + db.z + (float)f[6]);
    o[7] = (__bf16)silu(sb2.w + db.w + (float)f[7]);
    return o;
}

// ------------- fused edge MFMA kernel: block = 128 edges x 256 cols, K=256 -------------
// A[e][k] = silu(Sb[src][k] + D[dst][k] + Fp[e][k])  (Sb includes +b1)
// out = mean over 32-edge src groups of silu(A @ w2^T + b2) -> hcat agg half (bf16)
__global__ __launch_bounds__(256, 2) void edge_mfma(
        const float* __restrict__ Sb, const float* __restrict__ D,
        const __bf16* __restrict__ Fp, const __bf16* __restrict__ W2,
        const float* __restrict__ b2, __bf16* __restrict__ hcat) {
    __shared__ __bf16 As[2][128*40];
    __shared__ __bf16 Bs[2][256*40];
    int tid = threadIdx.x;
    int lane = tid & 63;
    int wid = tid >> 6;
    int wm = wid >> 1, wn = wid & 1;
    int r16 = lane & 15, g4 = lane >> 4;
    int ebase = blockIdx.x * 128;
    int graph = ebase >> 10;
    int s0 = ebase >> 5;                 // 4 src rows: s0..s0+3
    int le = tid >> 1, half = tid & 1;
    int srcrow = s0 + (le >> 5);
    int dstrow = graph*32 + (le & 31);
    const float*  sbp = Sb + (size_t)srcrow*256 + half*16;
    const float*  dp  = D  + (size_t)dstrow*256 + half*16;
    const __bf16* fpp = Fp + (size_t)(ebase + le)*256 + half*16;
    const __bf16* w2p = W2 + (size_t)tid*256;
    int awoff = le*40 + half*16;
    int bwoff = tid*40;

    f32x4 acc[4][8] = {};
    float4 rs0, rs1, rs2, rs3, rd0, rd1, rd2, rd3;
    bf16x8 rf0, rf1;
    uint4 rw0, rw1, rw2, rw3;

#define EDGE_LOADC(c) { \
    rs0 = *(const float4*)(sbp + (c)*32);      rs1 = *(const float4*)(sbp + (c)*32 + 4);  \
    rs2 = *(const float4*)(sbp + (c)*32 + 8);  rs3 = *(const float4*)(sbp + (c)*32 + 12); \
    rd0 = *(const float4*)(dp  + (c)*32);      rd1 = *(const float4*)(dp  + (c)*32 + 4);  \
    rd2 = *(const float4*)(dp  + (c)*32 + 8);  rd3 = *(const float4*)(dp  + (c)*32 + 12); \
    rf0 = *(const bf16x8*)(fpp + (c)*32);      rf1 = *(const bf16x8*)(fpp + (c)*32 + 8);  \
    rw0 = *(const uint4*)(w2p + (c)*32);       rw1 = *(const uint4*)(w2p + (c)*32 + 8);   \
    rw2 = *(const uint4*)(w2p + (c)*32 + 16);  rw3 = *(const uint4*)(w2p + (c)*32 + 24); }

#define EDGE_WRITEC(buf) { \
    bf16x8 av0 = packA8(rs0, rs1, rd0, rd1, rf0); \
    bf16x8 av1 = packA8(rs2, rs3, rd2, rd3, rf1); \
    *(bf16x8*)&As[buf][awoff]     = av0; \
    *(bf16x8*)&As[buf][awoff + 8] = av1; \
    *(uint4*)&Bs[buf][bwoff]      = rw0;  *(uint4*)&Bs[buf][bwoff + 8]  = rw1; \
    *(uint4*)&Bs[buf][bwoff + 16] = rw2;  *(uint4*)&Bs[buf][bwoff + 24] = rw3; }

    EDGE_LOADC(0);
    EDGE_WRITEC(0);
    __syncthreads();
    for (int c = 0; c < 8; ++c) {
        int cur = c & 1;
        if (c < 7) EDGE_LOADC(c + 1);
        bf16x8 af[4];
        #pragma unroll
        for (int mt = 0; mt < 4; ++mt)
            af[mt] = *(const bf16x8*)&As[cur][(wm*64 + mt*16 + r16)*40 + g4*8];
        #pragma unroll
        for (int nt = 0; nt < 8; ++nt) {
            bf16x8 bfg = *(const bf16x8*)&Bs[cur][(wn*128 + nt*16 + r16)*40 + g4*8];
            #pragma unroll
            for (int mt = 0; mt < 4; ++mt)
                acc[mt][nt] = __builtin_amdgcn_mfma_f32_16x16x32_bf16(af[mt], bfg, acc[mt][nt], 0, 0, 0);
        }
        if (c < 7) EDGE_WRITEC(cur ^ 1);
        __syncthreads();
    }
#undef EDGE_LOADC
#undef EDGE_WRITEC

    const float inv32 = 1.0f / 32.0f;
    #pragma unroll
    for (int nt = 0; nt < 8; ++nt) {
        int col = wn*128 + nt*16 + r16;
        float bb = b2[col];
        float p0 = 0.f, p1 = 0.f;
        #pragma unroll
        for (int r = 0; r < 4; ++r) {
            p0 += silu(acc[0][nt][r] + bb) + silu(acc[1][nt][r] + bb);
            p1 += silu(acc[2][nt][r] + bb) + silu(acc[3][nt][r] + bb);
        }
        p0 += __shfl_xor(p0, 16); p0 += __shfl_xor(p0, 32);
        p1 += __shfl_xor(p1, 16); p1 += __shfl_xor(p1, 32);
        if (lane < 16) {
            int sA = s0 + wm*2;
            hcat[(size_t)sA*512 + 256 + col]       = (__bf16)(p0 * inv32);
            hcat[(size_t)(sA + 1)*512 + 256 + col] = (__bf16)(p1 * inv32);
        }
    }
}

// ---------------- heads ----------------
__global__ void coord_equiv_kernel(const float* __restrict__ h,
                                   const float* __restrict__ coord_w,
                                   const float* __restrict__ G,
                                   const int* __restrict__ invp,
                                   float* __restrict__ out_x) {
    int b = blockIdx.x;
    int tid = threadIdx.x; // 128
    __shared__ float cd[kNN][4];
    if (tid < kNN*3) {
        int nl = tid / 3, j = tid - nl*3;
        const float* hr = h + (size_t)(b*kNN + nl)*kH;
        const float* wr = coord_w + (size_t)j*kH;
        float acc = 0.f;
        #pragma unroll 4
        for (int k = 0; k < kH; ++k) acc += hr[k]*wr[k];
        cd[nl][j] = acc;
    }
    __syncthreads();
    if (tid < kNN*3) {
        int nl = tid / 3, j = tid - nl*3;
        float acc = 0.f;
        for (int g = 0; g < kGS; ++g) {
            int bg = b*kGS + g;
            int p = invp[bg*kNN + nl];
            const float* Gr = G + (size_t)bg*16 + j*4;
            acc += cd[p][0]*Gr[0] + cd[p][1]*Gr[1] + cd[p][2]*Gr[2] + Gr[3];
        }
        out_x[(size_t)(b*kNN + nl)*3 + j] = acc * (1.0f/kGS);
    }
}

__global__ void graphfeat_kernel(const float* __restrict__ h,
                                 const float* __restrict__ lattice_w,
                                 float* __restrict__ out_lat) {
    int g = blockIdx.x;
    int c = threadIdx.x;
    __shared__ float gf[kH];
    float s = 0.f;
    for (int nl = 0; nl < kNN; ++nl) s += h[(size_t)(g*kNN + nl)*kH + c];
    gf[c] = s * (1.0f/kNN);
    __syncthreads();
    if (c < 6) {
        const float* wr = lattice_w + (size_t)c*kH;
        float acc = 0.f;
        #pragma unroll 4
        for (int k = 0; k < kH; ++k) acc += gf[k]*wr[k];
        out_lat[g*6 + c] = acc;
    }
}

} // namespace

extern "C" void kernel_launch(void* const* d_in, const int* in_sizes, int n_in,
                              void* d_out, int out_size, void* d_ws, size_t ws_size,
                              hipStream_t stream) {
    (void)in_sizes; (void)n_in; (void)out_size; (void)ws_size;
    const float* t         = (const float*)d_in[0];
    const float* atom      = (const float*)d_in[1];
    const float* frac      = (const float*)d_in[2];
    const float* lattices  = (const float*)d_in[3];
    const float* G         = (const float*)d_in[4];
    const float* k_mean    = (const float*)d_in[5];
    const float* k_std     = (const float*)d_in[6];
    const float* k_mask    = (const float*)d_in[7];
    const float* k_bias    = (const float*)d_in[8];
    const float* emb_w     = (const float*)d_in[9];
    const float* emb_b     = (const float*)d_in[10];
    const float* latent_w  = (const float*)d_in[11];
    const float* latent_b  = (const float*)d_in[12];
    const float* edge_w1   = (const float*)d_in[13];
    const float* edge_b1   = (const float*)d_in[14];
    const float* edge_w2   = (const float*)d_in[15];
    const float* edge_b2   = (const float*)d_in[16];
    const float* node_w1   = (const float*)d_in[17];
    const float* node_b1   = (const float*)d_in[18];
    const float* node_w2   = (const float*)d_in[19];
    const float* node_b2   = (const float*)d_in[20];
    const float* coord_w   = (const float*)d_in[21];
    const float* lattice_w = (const float*)d_in[22];
    const int*   invp      = (const int*)d_in[25];

    float* out_x   = (float*)d_out;            // [4096,3]
    float* out_lat = (float*)d_out + kN*3;     // [128,6]

    char* base = (char*)d_ws;
    size_t off = 0;
    auto carve = [&](size_t bytes) { char* p = base + off; off += bytes; return p; };
    float*  ltl   = (float*)carve(8192);
    float*  h     = (float*)carve(4194304);          // [4096][256] fp32
    float*  Sbuf  = (float*)carve(4194304);          // S + b1
    float*  Dbuf  = (float*)carve(4194304);
    __bf16* hcat  = (__bf16*)carve(4194304);         // [4096][512] bf16: [h | agg]
    __bf16* t1    = (__bf16*)carve(2097152);         // [4096][256] bf16
    __bf16* fb    = (__bf16*)carve(25165824);        // feats bf16 [131072][96]
    __bf16* Fp    = (__bf16*)carve(67108864);        // [131072][256] bf16
    __bf16* w1ab  = (__bf16*)carve(1048576);         // [L][512][256]
    __bf16* w1c   = (__bf16*)carve(262144);          // [L][256][96]
    __bf16* w2b   = (__bf16*)carve(524288);          // [L][256][256]
    __bf16* nw1b  = (__bf16*)carve(1048576);         // [L][256][512]
    __bf16* nw2b  = (__bf16*)carve(524288);          // [L][256][256]

    lattice_kernel<<<1, 128, 0, stream>>>(lattices, k_mean, k_std, k_mask, k_bias, ltl);
    feats_bf_kernel<<<kE/256, 256, 0, stream>>>(frac, lattices, ltl, fb);
    conv_w1ab<<<(4*512*256)/256, 256, 0, stream>>>(edge_w1, w1ab);
    conv_w1c<<<(4*256*kKF)/256, 256, 0, stream>>>(edge_w1, w1c);
    conv_f2b<<<(4*256*256)/256, 256, 0, stream>>>(edge_w2, w2b, 4*256*256);
    conv_f2b<<<(4*256*512)/256, 256, 0, stream>>>(node_w1, nw1b, 4*256*512);
    conv_f2b<<<(4*256*256)/256, 256, 0, stream>>>(node_w2, nw2b, 4*256*256);
    embed_kernel<<<kN, 256, 0, stream>>>(atom, t, emb_w, emb_b, latent_w, latent_b, h, hcat);

    for (int l = 0; l < kL; ++l) {
        // S/D: [4096,256(of 512)] @ w1ab[512][256]^T
        gemm_bf16<256, 0><<<dim3(32, 4), 256, 0, stream>>>(
            hcat, 512, w1ab + (size_t)l*512*256, 256,
            edge_b1 + l*256, Sbuf, Dbuf, nullptr, nullptr, nullptr);
        // Fproj: feats[131072,96] @ w1c[256][96]^T -> bf16
        gemm_bf16<96, 1><<<dim3(1024, 2), 256, 0, stream>>>(
            fb, kKF, w1c + (size_t)l*256*kKF, kKF,
            nullptr, nullptr, nullptr, Fp, nullptr, nullptr);
        // fused edge MLP + scatter-mean -> hcat agg half
        edge_mfma<<<1024, 256, 0, stream>>>(
            Sbuf, Dbuf, Fp, w2b + (size_t)l*256*256, edge_b2 + l*256, hcat);
        // node MLP
        gemm_bf16<512, 2><<<dim3(32, 2), 256, 0, stream>>>(
            hcat, 512, nw1b + (size_t)l*256*512, 512,
            node_b1 + l*256, nullptr, nullptr, t1, nullptr, nullptr);
        gemm_bf16<256, 3><<<dim3(32, 2), 256, 0, stream>>>(
            t1, 256, nw2b + (size_t)l*256*256, 256,
            node_b2 + l*256, nullptr, nullptr, nullptr, h, hcat);
    }
    coord_equiv_kernel<<<kB, 128, 0, stream>>>(h, coord_w, G, invp, out_x);
    graphfeat_kernel<<<kB, 256, 0, stream>>>(h, lattice_w, out_lat);
}

// Round 4
// 1082.202 us; speedup vs baseline: 6.7003x; 1.1821x over previous
//
#include <hip/hip_runtime.h>
#include <math.h>

namespace {
constexpr int kH = 256;
constexpr int kL = 4;
constexpr int kAtomDim = 100;
constexpr int kB = 128;
constexpr int kNN = 32;
constexpr int kGS = 8;
constexpr int kN = kB * kNN;       // 4096
constexpr int kE = kB * kNN * kNN; // 131072
constexpr int kDinE = 581;
constexpr int kKF = 96;            // padded feature K (69 -> 96)
constexpr float kTwoPi = 6.28318530717958647692f;

typedef __bf16 bf16x8 __attribute__((ext_vector_type(8)));
typedef float  f32x4  __attribute__((ext_vector_type(4)));

__device__ __forceinline__ float silu(float x) { return x / (1.0f + expf(-x)); }

// ---------------- per-graph lattice: ltl = expm(S)^T expm(S) ----------------
__global__ void lattice_kernel(const float* __restrict__ lattices,
                               const float* __restrict__ k_mean,
                               const float* __restrict__ k_std,
                               const float* __restrict__ k_mask,
                               const float* __restrict__ k_bias,
                               float* __restrict__ ltl) {
    int b = threadIdx.x;
    if (b >= kB) return;
    double y[6];
    for (int k = 0; k < 6; ++k) {
        double v = (double)lattices[b * 6 + k] * (double)k_std[k] + (double)k_mean[k];
        y[k] = v * (double)k_mask[k] + (double)k_bias[k];
    }
    double A[9] = { y[0], y[3], y[4],
                    y[3], y[1], y[5],
                    y[4], y[5], y[2] };
    double nrm = 0.0;
    for (int i = 0; i < 3; ++i) {
        double r = fabs(A[i*3+0]) + fabs(A[i*3+1]) + fabs(A[i*3+2]);
        nrm = fmax(nrm, r);
    }
    int s = 0;
    while (nrm > 0.25 && s < 40) { nrm *= 0.5; s++; }
    double sc = 1.0;
    for (int i = 0; i < s; ++i) sc *= 0.5;
    for (int i = 0; i < 9; ++i) A[i] *= sc;
    double T[9]    = {1,0,0, 0,1,0, 0,0,1};
    double term[9] = {1,0,0, 0,1,0, 0,0,1};
    for (int it = 1; it <= 18; ++it) {
        double nt[9];
        double inv = 1.0 / (double)it;
        for (int i = 0; i < 3; ++i)
            for (int j = 0; j < 3; ++j) {
                double acc = 0.0;
                for (int k = 0; k < 3; ++k) acc += term[i*3+k] * A[k*3+j];
                nt[i*3+j] = acc * inv;
            }
        for (int i = 0; i < 9; ++i) { term[i] = nt[i]; T[i] += nt[i]; }
    }
    for (int q = 0; q < s; ++q) {
        double nt[9];
        for (int i = 0; i < 3; ++i)
            for (int j = 0; j < 3; ++j) {
                double acc = 0.0;
                for (int k = 0; k < 3; ++k) acc += T[i*3+k] * T[k*3+j];
                nt[i*3+j] = acc;
            }
        for (int i = 0; i < 9; ++i) T[i] = nt[i];
    }
    for (int i = 0; i < 3; ++i)
        for (int k = 0; k < 3; ++k) {
            double acc = 0.0;
            for (int j = 0; j < 3; ++j) acc += T[j*3+i] * T[j*3+k];
            ltl[b*9 + i*3 + k] = (float)acc;
        }
}

// ------- per-edge geometric features, bf16, padded to 96 cols with zeros -------
__global__ void feats_bf_kernel(const float* __restrict__ frac,
                                const float* __restrict__ lattices,
                                const float* __restrict__ ltl,
                                __bf16* __restrict__ out) {
    int e = blockIdx.x * blockDim.x + threadIdx.x;
    if (e >= kE) return;
    int g = e >> 10;
    int src = (g << 5) + ((e >> 5) & 31);
    int dst = (g << 5) + (e & 31);
    float d[3];
    #pragma unroll
    for (int c = 0; c < 3; ++c) {
        float z = kTwoPi * (frac[dst*3 + c] - frac[src*3 + c]);
        d[c] = atan2f(sinf(z), cosf(z)) * (1.0f / kTwoPi);
    }
    __bf16* f = out + (size_t)e * kKF;
    #pragma unroll
    for (int k = 0; k < 6; ++k) f[k] = (__bf16)lattices[g*6 + k];
    #pragma unroll
    for (int c = 0; c < 3; ++c)
        #pragma unroll
        for (int fr = 0; fr < 10; ++fr) {
            float v = d[c] * (kTwoPi * (float)fr);
            f[6  + c*10 + fr] = (__bf16)sinf(v);
            f[36 + c*10 + fr] = (__bf16)cosf(v);
        }
    float v0 = ltl[g*9+0]*d[0] + ltl[g*9+1]*d[1] + ltl[g*9+2]*d[2];
    float v1 = ltl[g*9+3]*d[0] + ltl[g*9+4]*d[1] + ltl[g*9+5]*d[2];
    float v2 = ltl[g*9+6]*d[0] + ltl[g*9+7]*d[1] + ltl[g*9+8]*d[2];
    float nr = sqrtf(v0*v0 + v1*v1 + v2*v2) + 1e-6f;
    f[66] = (__bf16)(v0/nr); f[67] = (__bf16)(v1/nr); f[68] = (__bf16)(v2/nr);
    #pragma unroll
    for (int k = 69; k < kKF; ++k) f[k] = (__bf16)0.0f;
}

// ---------------- weight / input conversion kernels ----------------
__global__ void conv_f2b(const float* __restrict__ s, __bf16* __restrict__ d, int n) {
    int i = blockIdx.x * 256 + threadIdx.x;
    if (i < n) d[i] = (__bf16)s[i];
}
// w1ab: [L][512][256]: rows 0..255 = w1[c][0:256] (S part), rows 256..511 = w1[c][256:512] (D part)
__global__ void conv_w1ab(const float* __restrict__ w1, __bf16* __restrict__ dst) {
    int i = blockIdx.x * 256 + threadIdx.x;   // 4*512*256
    int l = i >> 17;
    int rem = i & 131071;
    int r = rem >> 8;
    int k = rem & 255;
    float v = (r < 256) ? w1[((size_t)(l*256 + r))*kDinE + k]
                        : w1[((size_t)(l*256 + (r-256)))*kDinE + 256 + k];
    dst[i] = (__bf16)v;
}
// w1c: [L][256][96]: w1[n][512+k] for k<69 else 0
__global__ void conv_w1c(const float* __restrict__ w1, __bf16* __restrict__ dst) {
    int i = blockIdx.x * 256 + threadIdx.x;   // 4*256*96
    int l = i / (256*kKF);
    int rem = i - l*256*kKF;
    int n = rem / kKF;
    int k = rem - n*kKF;
    float v = (k < 69) ? w1[((size_t)(l*256 + n))*kDinE + 512 + k] : 0.0f;
    dst[i] = (__bf16)v;
}
// atom_types [4096][100] -> bf16 padded [4096][128]
__global__ void conv_atom(const float* __restrict__ a, __bf16* __restrict__ d) {
    int i = blockIdx.x * 256 + threadIdx.x;   // 4096*128
    int n = i >> 7, k = i & 127;
    d[i] = (__bf16)((k < kAtomDim) ? a[(size_t)n*kAtomDim + k] : 0.0f);
}
// emb_w [256][100] -> bf16 padded [256][128]
__global__ void conv_embw(const float* __restrict__ w, __bf16* __restrict__ d) {
    int i = blockIdx.x * 256 + threadIdx.x;   // 256*128
    int n = i >> 7, k = i & 127;
    d[i] = (__bf16)((k < kAtomDim) ? w[(size_t)n*kAtomDim + k] : 0.0f);
}
// time embedding -> tecat cols [256,384), repeated per node of graph
__global__ void temb_kernel(const float* __restrict__ t, __bf16* __restrict__ tecat) {
    int g = blockIdx.x;
    int tid = threadIdx.x;  // 128
    float tf = expf(-logf(10000.0f) * (float)(tid & 63) / 64.0f);
    float ta = t[g] * tf;
    float v = (tid < 64) ? cosf(ta) : sinf(ta);   // cos first
    __bf16 bv = (__bf16)v;
    #pragma unroll
    for (int nl = 0; nl < kNN; ++nl)
        tecat[((size_t)(g*kNN + nl))*384 + 256 + tid] = bv;
}

// ---------------- generic 128x128-tile bf16 GEMM: C = A[M][lda] @ W[N][ldw]^T ----------------
// EPI 0: Sb/D split (N=512): n<256 -> out0 = acc+bias, else out1 = acc
// EPI 1: outbf = bf16(acc)                        (stride ldo)
// EPI 2: outbf = bf16(silu(acc+bias))             (stride ldo)
// EPI 3: h += silu(acc+bias); write h fp32 + hcat bf16
// EPI 4: outbf = bf16(acc+bias)                   (stride ldo)
// EPI 5: h = acc+bias (init); write h fp32 + hcat bf16
template<int K, int EPI>
__global__ __launch_bounds__(256) void gemm_bf16(
        const __bf16* __restrict__ A, int lda,
        const __bf16* __restrict__ W, int ldw,
        const float* __restrict__ bias,
        float* __restrict__ out0, float* __restrict__ out1,
        __bf16* __restrict__ outbf, int ldo,
        float* __restrict__ hmaster, __bf16* __restrict__ hcat) {
    constexpr int NC = K / 32;
    __shared__ __bf16 As[2][128*40];
    __shared__ __bf16 Bs[2][128*40];
    int tid = threadIdx.x;
    int lane = tid & 63;
    int wid = tid >> 6;
    int wm = wid >> 1, wn = wid & 1;
    int r16 = lane & 15, g4 = lane >> 4;
    int mbase = blockIdx.x * 128;
    int nbase = blockIdx.y * 128;
    int srow = tid >> 1, shalf = tid & 1;
    const __bf16* agp = A + (size_t)(mbase + srow)*lda + shalf*16;
    const __bf16* wgp = W + (size_t)(nbase + srow)*ldw + shalf*16;
    int woff = srow*40 + shalf*16;

    f32x4 acc[4][4] = {};
    uint4 ra0, ra1, rb0, rb1;
    ra0 = *(const uint4*)(agp);     ra1 = *(const uint4*)(agp + 8);
    rb0 = *(const uint4*)(wgp);     rb1 = *(const uint4*)(wgp + 8);
    *(uint4*)&As[0][woff]     = ra0;  *(uint4*)&As[0][woff + 8] = ra1;
    *(uint4*)&Bs[0][woff]     = rb0;  *(uint4*)&Bs[0][woff + 8] = rb1;
    __syncthreads();
    for (int c = 0; c < NC; ++c) {
        int cur = c & 1;
        if (c + 1 < NC) {
            ra0 = *(const uint4*)(agp + (c+1)*32);  ra1 = *(const uint4*)(agp + (c+1)*32 + 8);
            rb0 = *(const uint4*)(wgp + (c+1)*32);  rb1 = *(const uint4*)(wgp + (c+1)*32 + 8);
        }
        bf16x8 af[4], bfg[4];
        #pragma unroll
        for (int mt = 0; mt < 4; ++mt)
            af[mt] = *(const bf16x8*)&As[cur][(wm*64 + mt*16 + r16)*40 + g4*8];
        #pragma unroll
        for (int nt = 0; nt < 4; ++nt)
            bfg[nt] = *(const bf16x8*)&Bs[cur][(wn*64 + nt*16 + r16)*40 + g4*8];
        #pragma unroll
        for (int mt = 0; mt < 4; ++mt)
            #pragma unroll
            for (int nt = 0; nt < 4; ++nt)
                acc[mt][nt] = __builtin_amdgcn_mfma_f32_16x16x32_bf16(af[mt], bfg[nt], acc[mt][nt], 0, 0, 0);
        if (c + 1 < NC) {
            int nxt = cur ^ 1;
            *(uint4*)&As[nxt][woff]     = ra0;  *(uint4*)&As[nxt][woff + 8] = ra1;
            *(uint4*)&Bs[nxt][woff]     = rb0;  *(uint4*)&Bs[nxt][woff + 8] = rb1;
        }
        __syncthreads();
    }
    #pragma unroll
    for (int mt = 0; mt < 4; ++mt)
        #pragma unroll
        for (int nt = 0; nt < 4; ++nt) {
            int n = nbase + wn*64 + nt*16 + r16;
            #pragma unroll
            for (int r = 0; r < 4; ++r) {
                int m = mbase + wm*64 + mt*16 + g4*4 + r;
                float v = acc[mt][nt][r];
                if (EPI == 0) {
                    if (n < 256) out0[(size_t)m*256 + n] = v + bias[n];
                    else         out1[(size_t)m*256 + (n - 256)] = v;
                } else if (EPI == 1) {
                    outbf[(size_t)m*ldo + n] = (__bf16)v;
                } else if (EPI == 2) {
                    outbf[(size_t)m*ldo + n] = (__bf16)silu(v + bias[n]);
                } else if (EPI == 3) {
                    float hv = hmaster[(size_t)m*256 + n] + silu(v + bias[n]);
                    hmaster[(size_t)m*256 + n] = hv;
                    hcat[(size_t)m*512 + n] = (__bf16)hv;
                } else if (EPI == 4) {
                    outbf[(size_t)m*ldo + n] = (__bf16)(v + bias[n]);
                } else {
                    float hv = v + bias[n];
                    hmaster[(size_t)m*256 + n] = hv;
                    hcat[(size_t)m*512 + n] = (__bf16)hv;
                }
            }
        }
}

// ---- helper: 4+4 fp32 + 8 bf16 feature -> silu -> bf16x8 ----
__device__ __forceinline__ bf16x8 packA8(float4 sa, float4 sb2, float4 da, float4 db, bf16x8 f) {
    bf16x8 o;
    o[0] = (__bf16)silu(sa.x  + da.x + (float)f[0]);
    o[1] = (__bf16)silu(sa.y  + da.y + (float)f[1]);
    o[2] = (__bf16)silu(sa.z  + da.z + (float)f[2]);
    o[3] = (__bf16)silu(sa.w  + da.w + (float)f[3]);
    o[4] = (__bf16)silu(sb2.x + db.x + (float)f[4]);
    o[5] = (__bf16)silu(sb2.y + db.y + (float)f[5]);
    o[6] = (__bf16)silu(sb2.z + db.z + (float)f[6]);
    o[7] = (__bf16)silu(sb2.w + db.w + (float)f[7]);
    return o;
}

// ------------- fused edge MFMA kernel: block = 128 edges x 256 cols, K=256 -------------
// A[e][k] = silu(Sb[src][k] + D[dst][k] + Fp[e][k])  (Sb includes +b1)
// out = mean over 32-edge src groups of silu(A @ w2^T + b2) -> hcat agg half (bf16)
__global__ __launch_bounds__(256, 2) void edge_mfma(
        const float* __restrict__ Sb, const float* __restrict__ D,
        const __bf16* __restrict__ Fp, const __bf16* __restrict__ W2,
        const float* __restrict__ b2, __bf16* __restrict__ hcat) {
    __shared__ __bf16 As[2][128*40];
    __shared__ __bf16 Bs[2][256*40];
    int tid = threadIdx.x;
    int lane = tid & 63;
    int wid = tid >> 6;
    int wm = wid >> 1, wn = wid & 1;
    int r16 = lane & 15, g4 = lane >> 4;
    int ebase = blockIdx.x * 128;
    int graph = ebase >> 10;
    int s0 = ebase >> 5;                 // 4 src rows: s0..s0+3
    int le = tid >> 1, half = tid & 1;
    int srcrow = s0 + (le >> 5);
    int dstrow = graph*32 + (le & 31);
    const float*  sbp = Sb + (size_t)srcrow*256 + half*16;
    const float*  dp  = D  + (size_t)dstrow*256 + half*16;
    const __bf16* fpp = Fp + (size_t)(ebase + le)*256 + half*16;
    const __bf16* w2p = W2 + (size_t)tid*256;
    int awoff = le*40 + half*16;
    int bwoff = tid*40;

    f32x4 acc[4][8] = {};
    float4 rs0, rs1, rs2, rs3, rd0, rd1, rd2, rd3;
    bf16x8 rf0, rf1;
    uint4 rw0, rw1, rw2, rw3;

#define EDGE_LOADC(c) { \
    rs0 = *(const float4*)(sbp + (c)*32);      rs1 = *(const float4*)(sbp + (c)*32 + 4);  \
    rs2 = *(const float4*)(sbp + (c)*32 + 8);  rs3 = *(const float4*)(sbp + (c)*32 + 12); \
    rd0 = *(const float4*)(dp  + (c)*32);      rd1 = *(const float4*)(dp  + (c)*32 + 4);  \
    rd2 = *(const float4*)(dp  + (c)*32 + 8);  rd3 = *(const float4*)(dp  + (c)*32 + 12); \
    rf0 = *(const bf16x8*)(fpp + (c)*32);      rf1 = *(const bf16x8*)(fpp + (c)*32 + 8);  \
    rw0 = *(const uint4*)(w2p + (c)*32);       rw1 = *(const uint4*)(w2p + (c)*32 + 8);   \
    rw2 = *(const uint4*)(w2p + (c)*32 + 16);  rw3 = *(const uint4*)(w2p + (c)*32 + 24); }

#define EDGE_WRITEC(buf) { \
    bf16x8 av0 = packA8(rs0, rs1, rd0, rd1, rf0); \
    bf16x8 av1 = packA8(rs2, rs3, rd2, rd3, rf1); \
    *(bf16x8*)&As[buf][awoff]     = av0; \
    *(bf16x8*)&As[buf][awoff + 8] = av1; \
    *(uint4*)&Bs[buf][bwoff]      = rw0;  *(uint4*)&Bs[buf][bwoff + 8]  = rw1; \
    *(uint4*)&Bs[buf][bwoff + 16] = rw2;  *(uint4*)&Bs[buf][bwoff + 24] = rw3; }

    EDGE_LOADC(0);
    EDGE_WRITEC(0);
    __syncthreads();
    for (int c = 0; c < 8; ++c) {
        int cur = c & 1;
        if (c < 7) EDGE_LOADC(c + 1);
        bf16x8 af[4];
        #pragma unroll
        for (int mt = 0; mt < 4; ++mt)
            af[mt] = *(const bf16x8*)&As[cur][(wm*64 + mt*16 + r16)*40 + g4*8];
        #pragma unroll
        for (int nt = 0; nt < 8; ++nt) {
            bf16x8 bfg = *(const bf16x8*)&Bs[cur][(wn*128 + nt*16 + r16)*40 + g4*8];
            #pragma unroll
            for (int mt = 0; mt < 4; ++mt)
                acc[mt][nt] = __builtin_amdgcn_mfma_f32_16x16x32_bf16(af[mt], bfg, acc[mt][nt], 0, 0, 0);
        }
        if (c < 7) EDGE_WRITEC(cur ^ 1);
        __syncthreads();
    }
#undef EDGE_LOADC
#undef EDGE_WRITEC

    const float inv32 = 1.0f / 32.0f;
    #pragma unroll
    for (int nt = 0; nt < 8; ++nt) {
        int col = wn*128 + nt*16 + r16;
        float bb = b2[col];
        float p0 = 0.f, p1 = 0.f;
        #pragma unroll
        for (int r = 0; r < 4; ++r) {
            p0 += silu(acc[0][nt][r] + bb) + silu(acc[1][nt][r] + bb);
            p1 += silu(acc[2][nt][r] + bb) + silu(acc[3][nt][r] + bb);
        }
        p0 += __shfl_xor(p0, 16); p0 += __shfl_xor(p0, 32);
        p1 += __shfl_xor(p1, 16); p1 += __shfl_xor(p1, 32);
        if (lane < 16) {
            int sA = s0 + wm*2;
            hcat[(size_t)sA*512 + 256 + col]       = (__bf16)(p0 * inv32);
            hcat[(size_t)(sA + 1)*512 + 256 + col] = (__bf16)(p1 * inv32);
        }
    }
}

// ---------------- heads ----------------
__global__ void coord_equiv_kernel(const float* __restrict__ h,
                                   const float* __restrict__ coord_w,
                                   const float* __restrict__ G,
                                   const int* __restrict__ invp,
                                   float* __restrict__ out_x) {
    int b = blockIdx.x;
    int tid = threadIdx.x; // 128
    __shared__ float cd[kNN][4];
    if (tid < kNN*3) {
        int nl = tid / 3, j = tid - nl*3;
        const float* hr = h + (size_t)(b*kNN + nl)*kH;
        const float* wr = coord_w + (size_t)j*kH;
        float acc = 0.f;
        #pragma unroll 4
        for (int k = 0; k < kH; ++k) acc += hr[k]*wr[k];
        cd[nl][j] = acc;
    }
    __syncthreads();
    if (tid < kNN*3) {
        int nl = tid / 3, j = tid - nl*3;
        float acc = 0.f;
        for (int g = 0; g < kGS; ++g) {
            int bg = b*kGS + g;
            int p = invp[bg*kNN + nl];
            const float* Gr = G + (size_t)bg*16 + j*4;
            acc += cd[p][0]*Gr[0] + cd[p][1]*Gr[1] + cd[p][2]*Gr[2] + Gr[3];
        }
        out_x[(size_t)(b*kNN + nl)*3 + j] = acc * (1.0f/kGS);
    }
}

__global__ void graphfeat_kernel(const float* __restrict__ h,
                                 const float* __restrict__ lattice_w,
                                 float* __restrict__ out_lat) {
    int g = blockIdx.x;
    int c = threadIdx.x;
    __shared__ float gf[kH];
    float s = 0.f;
    for (int nl = 0; nl < kNN; ++nl) s += h[(size_t)(g*kNN + nl)*kH + c];
    gf[c] = s * (1.0f/kNN);
    __syncthreads();
    if (c < 6) {
        const float* wr = lattice_w + (size_t)c*kH;
        float acc = 0.f;
        #pragma unroll 4
        for (int k = 0; k < kH; ++k) acc += gf[k]*wr[k];
        out_lat[g*6 + c] = acc;
    }
}

} // namespace

extern "C" void kernel_launch(void* const* d_in, const int* in_sizes, int n_in,
                              void* d_out, int out_size, void* d_ws, size_t ws_size,
                              hipStream_t stream) {
    (void)in_sizes; (void)n_in; (void)out_size; (void)ws_size;
    const float* t         = (const float*)d_in[0];
    const float* atom      = (const float*)d_in[1];
    const float* frac      = (const float*)d_in[2];
    const float* lattices  = (const float*)d_in[3];
    const float* G         = (const float*)d_in[4];
    const float* k_mean    = (const float*)d_in[5];
    const float* k_std     = (const float*)d_in[6];
    const float* k_mask    = (const float*)d_in[7];
    const float* k_bias    = (const float*)d_in[8];
    const float* emb_w     = (const float*)d_in[9];
    const float* emb_b     = (const float*)d_in[10];
    const float* latent_w  = (const float*)d_in[11];
    const float* latent_b  = (const float*)d_in[12];
    const float* edge_w1   = (const float*)d_in[13];
    const float* edge_b1   = (const float*)d_in[14];
    const float* edge_w2   = (const float*)d_in[15];
    const float* edge_b2   = (const float*)d_in[16];
    const float* node_w1   = (const float*)d_in[17];
    const float* node_b1   = (const float*)d_in[18];
    const float* node_w2   = (const float*)d_in[19];
    const float* node_b2   = (const float*)d_in[20];
    const float* coord_w   = (const float*)d_in[21];
    const float* lattice_w = (const float*)d_in[22];
    const int*   invp      = (const int*)d_in[25];

    float* out_x   = (float*)d_out;            // [4096,3]
    float* out_lat = (float*)d_out + kN*3;     // [128,6]

    char* base = (char*)d_ws;
    size_t off = 0;
    auto carve = [&](size_t bytes) { char* p = base + off; off += bytes; return p; };
    float*  ltl    = (float*)carve(8192);
    float*  h      = (float*)carve(4194304);          // [4096][256] fp32
    float*  Sbuf   = (float*)carve(4194304);          // S + b1
    float*  Dbuf   = (float*)carve(4194304);
    __bf16* hcat   = (__bf16*)carve(4194304);         // [4096][512] bf16: [h | agg]
    __bf16* t1     = (__bf16*)carve(2097152);         // [4096][256] bf16
    __bf16* fb     = (__bf16*)carve(25165824);        // feats bf16 [131072][96]
    __bf16* Fp     = (__bf16*)carve(67108864);        // [131072][256] bf16
    __bf16* w1ab   = (__bf16*)carve(1048576);         // [L][512][256]
    __bf16* w1c    = (__bf16*)carve(262144);          // [L][256][96]
    __bf16* w2b    = (__bf16*)carve(524288);          // [L][256][256]
    __bf16* nw1b   = (__bf16*)carve(1048576);         // [L][256][512]
    __bf16* nw2b   = (__bf16*)carve(524288);          // [L][256][256]
    __bf16* at_bf  = (__bf16*)carve(1048576);         // [4096][128] atom bf16 padded
    __bf16* embwb  = (__bf16*)carve(65536);           // [256][128]
    __bf16* latwb  = (__bf16*)carve(196608);          // [256][384]
    __bf16* tecat  = (__bf16*)carve(3145728);         // [4096][384]: [h0 | temb]

    lattice_kernel<<<1, 128, 0, stream>>>(lattices, k_mean, k_std, k_mask, k_bias, ltl);
    feats_bf_kernel<<<kE/256, 256, 0, stream>>>(frac, lattices, ltl, fb);
    conv_w1ab<<<(4*512*256)/256, 256, 0, stream>>>(edge_w1, w1ab);
    conv_w1c<<<(4*256*kKF)/256, 256, 0, stream>>>(edge_w1, w1c);
    conv_f2b<<<(4*256*256)/256, 256, 0, stream>>>(edge_w2, w2b, 4*256*256);
    conv_f2b<<<(4*256*512)/256, 256, 0, stream>>>(node_w1, nw1b, 4*256*512);
    conv_f2b<<<(4*256*256)/256, 256, 0, stream>>>(node_w2, nw2b, 4*256*256);
    conv_atom<<<(kN*128)/256, 256, 0, stream>>>(atom, at_bf);
    conv_embw<<<(256*128)/256, 256, 0, stream>>>(emb_w, embwb);
    conv_f2b<<<(256*384)/256, 256, 0, stream>>>(latent_w, latwb, 256*384);
    temb_kernel<<<kB, 128, 0, stream>>>(t, tecat);

    // embed GEMM1: h0 = at_bf[4096,128] @ embwb[256,128]^T + emb_b -> tecat[:, :256]
    gemm_bf16<128, 4><<<dim3(32, 2), 256, 0, stream>>>(
        at_bf, 128, embwb, 128, emb_b,
        nullptr, nullptr, tecat, 384, nullptr, nullptr);
    // embed GEMM2: h = tecat[4096,384] @ latwb[256,384]^T + latent_b -> h fp32 + hcat bf16
    gemm_bf16<384, 5><<<dim3(32, 2), 256, 0, stream>>>(
        tecat, 384, latwb, 384, latent_b,
        nullptr, nullptr, nullptr, 0, h, hcat);

    for (int l = 0; l < kL; ++l) {
        // S/D: [4096,256(of 512)] @ w1ab[512][256]^T
        gemm_bf16<256, 0><<<dim3(32, 4), 256, 0, stream>>>(
            hcat, 512, w1ab + (size_t)l*512*256, 256,
            edge_b1 + l*256, Sbuf, Dbuf, nullptr, 0, nullptr, nullptr);
        // Fproj: feats[131072,96] @ w1c[256][96]^T -> bf16
        gemm_bf16<96, 1><<<dim3(1024, 2), 256, 0, stream>>>(
            fb, kKF, w1c + (size_t)l*256*kKF, kKF,
            nullptr, nullptr, nullptr, Fp, 256, nullptr, nullptr);
        // fused edge MLP + scatter-mean -> hcat agg half
        edge_mfma<<<1024, 256, 0, stream>>>(
            Sbuf, Dbuf, Fp, w2b + (size_t)l*256*256, edge_b2 + l*256, hcat);
        // node MLP
        gemm_bf16<512, 2><<<dim3(32, 2), 256, 0, stream>>>(
            hcat, 512, nw1b + (size_t)l*256*512, 512,
            node_b1 + l*256, nullptr, nullptr, t1, 256, nullptr, nullptr);
        gemm_bf16<256, 3><<<dim3(32, 2), 256, 0, stream>>>(
            t1, 256, nw2b + (size_t)l*256*256, 256,
            node_b2 + l*256, nullptr, nullptr, nullptr, 0, h, hcat);
    }
    coord_equiv_kernel<<<kB, 128, 0, stream>>>(h, coord_w, G, invp, out_x);
    graphfeat_kernel<<<kB, 256, 0, stream>>>(h, lattice_w, out_lat);
}

// Round 5
// 800.630 us; speedup vs baseline: 9.0568x; 1.3517x over previous
//
#include <hip/hip_runtime.h>
#include <math.h>

namespace {
constexpr int kH = 256;
constexpr int kL = 4;
constexpr int kAtomDim = 100;
constexpr int kB = 128;
constexpr int kNN = 32;
constexpr int kGS = 8;
constexpr int kN = kB * kNN;       // 4096
constexpr int kE = kB * kNN * kNN; // 131072
constexpr int kDinE = 581;
constexpr int kKF = 96;            // padded feature K (69 -> 96)
constexpr float kTwoPi = 6.28318530717958647692f;

typedef __bf16 bf16x8 __attribute__((ext_vector_type(8)));
typedef float  f32x4  __attribute__((ext_vector_type(4)));

__device__ __forceinline__ float fsilu(float x) {
    // x * rcp(1+e^-x): v_rcp_f32 + native exp, ~1e-7 rel err, invisible at bf16
    return x * __builtin_amdgcn_rcpf(1.0f + __expf(-x));
}

// ---------------- per-graph lattice: ltl = expm(S)^T expm(S) ----------------
__global__ void lattice_kernel(const float* __restrict__ lattices,
                               const float* __restrict__ k_mean,
                               const float* __restrict__ k_std,
                               const float* __restrict__ k_mask,
                               const float* __restrict__ k_bias,
                               float* __restrict__ ltl) {
    int b = threadIdx.x;
    if (b >= kB) return;
    double y[6];
    for (int k = 0; k < 6; ++k) {
        double v = (double)lattices[b * 6 + k] * (double)k_std[k] + (double)k_mean[k];
        y[k] = v * (double)k_mask[k] + (double)k_bias[k];
    }
    double A[9] = { y[0], y[3], y[4],
                    y[3], y[1], y[5],
                    y[4], y[5], y[2] };
    double nrm = 0.0;
    for (int i = 0; i < 3; ++i) {
        double r = fabs(A[i*3+0]) + fabs(A[i*3+1]) + fabs(A[i*3+2]);
        nrm = fmax(nrm, r);
    }
    int s = 0;
    while (nrm > 0.25 && s < 40) { nrm *= 0.5; s++; }
    double sc = 1.0;
    for (int i = 0; i < s; ++i) sc *= 0.5;
    for (int i = 0; i < 9; ++i) A[i] *= sc;
    double T[9]    = {1,0,0, 0,1,0, 0,0,1};
    double term[9] = {1,0,0, 0,1,0, 0,0,1};
    for (int it = 1; it <= 18; ++it) {
        double nt[9];
        double inv = 1.0 / (double)it;
        for (int i = 0; i < 3; ++i)
            for (int j = 0; j < 3; ++j) {
                double acc = 0.0;
                for (int k = 0; k < 3; ++k) acc += term[i*3+k] * A[k*3+j];
                nt[i*3+j] = acc * inv;
            }
        for (int i = 0; i < 9; ++i) { term[i] = nt[i]; T[i] += nt[i]; }
    }
    for (int q = 0; q < s; ++q) {
        double nt[9];
        for (int i = 0; i < 3; ++i)
            for (int j = 0; j < 3; ++j) {
                double acc = 0.0;
                for (int k = 0; k < 3; ++k) acc += T[i*3+k] * T[k*3+j];
                nt[i*3+j] = acc;
            }
        for (int i = 0; i < 9; ++i) T[i] = nt[i];
    }
    for (int i = 0; i < 3; ++i)
        for (int k = 0; k < 3; ++k) {
            double acc = 0.0;
            for (int j = 0; j < 3; ++j) acc += T[j*3+i] * T[j*3+k];
            ltl[b*9 + i*3 + k] = (float)acc;
        }
}

// ------- per-edge geometric features, bf16, padded to 96; register-built + uint4 stores ---
__global__ void feats_bf_kernel(const float* __restrict__ frac,
                                const float* __restrict__ lattices,
                                const float* __restrict__ ltl,
                                __bf16* __restrict__ out) {
    int e = blockIdx.x * blockDim.x + threadIdx.x;
    if (e >= kE) return;
    int g = e >> 10;
    int src = (g << 5) + ((e >> 5) & 31);
    int dst = (g << 5) + (e & 31);
    float d[3];
    #pragma unroll
    for (int c = 0; c < 3; ++c) {
        float z = kTwoPi * (frac[dst*3 + c] - frac[src*3 + c]);
        d[c] = atan2f(sinf(z), cosf(z)) * (1.0f / kTwoPi);
    }
    __attribute__((aligned(16))) __bf16 f[kKF];
    #pragma unroll
    for (int k = 0; k < 6; ++k) f[k] = (__bf16)lattices[g*6 + k];
    #pragma unroll
    for (int c = 0; c < 3; ++c)
        #pragma unroll
        for (int fr = 0; fr < 10; ++fr) {
            float v = d[c] * (kTwoPi * (float)fr);
            f[6  + c*10 + fr] = (__bf16)sinf(v);
            f[36 + c*10 + fr] = (__bf16)cosf(v);
        }
    float v0 = ltl[g*9+0]*d[0] + ltl[g*9+1]*d[1] + ltl[g*9+2]*d[2];
    float v1 = ltl[g*9+3]*d[0] + ltl[g*9+4]*d[1] + ltl[g*9+5]*d[2];
    float v2 = ltl[g*9+6]*d[0] + ltl[g*9+7]*d[1] + ltl[g*9+8]*d[2];
    float nr = sqrtf(v0*v0 + v1*v1 + v2*v2) + 1e-6f;
    f[66] = (__bf16)(v0/nr); f[67] = (__bf16)(v1/nr); f[68] = (__bf16)(v2/nr);
    #pragma unroll
    for (int k = 69; k < kKF; ++k) f[k] = (__bf16)0.0f;
    uint4* dstp = (uint4*)(out + (size_t)e * kKF);
    const uint4* srcp = (const uint4*)f;
    #pragma unroll
    for (int i = 0; i < kKF/8; ++i) dstp[i] = srcp[i];
}

// ---------------- weight / input conversion kernels ----------------
__global__ void conv_f2b(const float* __restrict__ s, __bf16* __restrict__ d, int n) {
    int i = blockIdx.x * 256 + threadIdx.x;
    if (i < n) d[i] = (__bf16)s[i];
}
// w1ab: [L][512][256]: rows 0..255 = w1[c][0:256] (S part), rows 256..511 = w1[c][256:512] (D part)
__global__ void conv_w1ab(const float* __restrict__ w1, __bf16* __restrict__ dst) {
    int i = blockIdx.x * 256 + threadIdx.x;   // 4*512*256
    int l = i >> 17;
    int rem = i & 131071;
    int r = rem >> 8;
    int k = rem & 255;
    float v = (r < 256) ? w1[((size_t)(l*256 + r))*kDinE + k]
                        : w1[((size_t)(l*256 + (r-256)))*kDinE + 256 + k];
    dst[i] = (__bf16)v;
}
// w1c: [L][256][96]: w1[n][512+k] for k<69 else 0
__global__ void conv_w1c(const float* __restrict__ w1, __bf16* __restrict__ dst) {
    int i = blockIdx.x * 256 + threadIdx.x;   // 4*256*96
    int l = i / (256*kKF);
    int rem = i - l*256*kKF;
    int n = rem / kKF;
    int k = rem - n*kKF;
    float v = (k < 69) ? w1[((size_t)(l*256 + n))*kDinE + 512 + k] : 0.0f;
    dst[i] = (__bf16)v;
}
// atom_types [4096][100] -> bf16 padded [4096][128]
__global__ void conv_atom(const float* __restrict__ a, __bf16* __restrict__ d) {
    int i = blockIdx.x * 256 + threadIdx.x;   // 4096*128
    int n = i >> 7, k = i & 127;
    d[i] = (__bf16)((k < kAtomDim) ? a[(size_t)n*kAtomDim + k] : 0.0f);
}
// emb_w [256][100] -> bf16 padded [256][128]
__global__ void conv_embw(const float* __restrict__ w, __bf16* __restrict__ d) {
    int i = blockIdx.x * 256 + threadIdx.x;   // 256*128
    int n = i >> 7, k = i & 127;
    d[i] = (__bf16)((k < kAtomDim) ? w[(size_t)n*kAtomDim + k] : 0.0f);
}
// time embedding -> tecat cols [256,384), repeated per node of graph
__global__ void temb_kernel(const float* __restrict__ t, __bf16* __restrict__ tecat) {
    int g = blockIdx.x;
    int tid = threadIdx.x;  // 128
    float tf = expf(-logf(10000.0f) * (float)(tid & 63) / 64.0f);
    float ta = t[g] * tf;
    float v = (tid < 64) ? cosf(ta) : sinf(ta);   // cos first
    __bf16 bv = (__bf16)v;
    #pragma unroll
    for (int nl = 0; nl < kNN; ++nl)
        tecat[((size_t)(g*kNN + nl))*384 + 256 + tid] = bv;
}

// ---------------- generic 128x128-tile bf16 GEMM: C = A[M][lda] @ W[N][ldw]^T ----------------
// EPI 0: Sb/D split (N=512): n<256 -> out0 = acc+bias, else out1 = acc
// EPI 1: outbf = bf16(acc)                        (stride ldo)
// EPI 2: outbf = bf16(silu(acc+bias))             (stride ldo)
// EPI 3: h += silu(acc+bias); write h fp32 + hcat bf16
// EPI 4: outbf = bf16(acc+bias)                   (stride ldo)
// EPI 5: h = acc+bias (init); write h fp32 + hcat bf16
// EPI 6: A-build: outbf[m][n] = bf16(silu(acc + S[src(m)][n] + D[dst(m)][n]))  (m = edge)
// EPI 7: edge agg: per-src mean over 32 edges of silu(acc + bias[n]) -> hcat[src][256+n]
template<int K, int EPI>
__global__ __launch_bounds__(256) void gemm_bf16(
        const __bf16* __restrict__ A, int lda,
        const __bf16* __restrict__ W, int ldw,
        const float* __restrict__ bias,
        float* __restrict__ out0, float* __restrict__ out1,
        __bf16* __restrict__ outbf, int ldo,
        float* __restrict__ hmaster, __bf16* __restrict__ hcat) {
    constexpr int NC = K / 32;
    __shared__ __bf16 As[2][128*40];
    __shared__ __bf16 Bs[2][128*40];
    int tid = threadIdx.x;
    int lane = tid & 63;
    int wid = tid >> 6;
    int wm = wid >> 1, wn = wid & 1;
    int r16 = lane & 15, g4 = lane >> 4;
    int mbase = blockIdx.x * 128;
    int nbase = blockIdx.y * 128;
    int srow = tid >> 1, shalf = tid & 1;
    const __bf16* agp = A + (size_t)(mbase + srow)*lda + shalf*16;
    const __bf16* wgp = W + (size_t)(nbase + srow)*ldw + shalf*16;
    int woff = srow*40 + shalf*16;

    f32x4 acc[4][4] = {};
    uint4 ra0, ra1, rb0, rb1;
    ra0 = *(const uint4*)(agp);     ra1 = *(const uint4*)(agp + 8);
    rb0 = *(const uint4*)(wgp);     rb1 = *(const uint4*)(wgp + 8);
    *(uint4*)&As[0][woff]     = ra0;  *(uint4*)&As[0][woff + 8] = ra1;
    *(uint4*)&Bs[0][woff]     = rb0;  *(uint4*)&Bs[0][woff + 8] = rb1;
    __syncthreads();
    for (int c = 0; c < NC; ++c) {
        int cur = c & 1;
        if (c + 1 < NC) {
            ra0 = *(const uint4*)(agp + (c+1)*32);  ra1 = *(const uint4*)(agp + (c+1)*32 + 8);
            rb0 = *(const uint4*)(wgp + (c+1)*32);  rb1 = *(const uint4*)(wgp + (c+1)*32 + 8);
        }
        bf16x8 af[4], bfg[4];
        #pragma unroll
        for (int mt = 0; mt < 4; ++mt)
            af[mt] = *(const bf16x8*)&As[cur][(wm*64 + mt*16 + r16)*40 + g4*8];
        #pragma unroll
        for (int nt = 0; nt < 4; ++nt)
            bfg[nt] = *(const bf16x8*)&Bs[cur][(wn*64 + nt*16 + r16)*40 + g4*8];
        #pragma unroll
        for (int mt = 0; mt < 4; ++mt)
            #pragma unroll
            for (int nt = 0; nt < 4; ++nt)
                acc[mt][nt] = __builtin_amdgcn_mfma_f32_16x16x32_bf16(af[mt], bfg[nt], acc[mt][nt], 0, 0, 0);
        if (c + 1 < NC) {
            int nxt = cur ^ 1;
            *(uint4*)&As[nxt][woff]     = ra0;  *(uint4*)&As[nxt][woff + 8] = ra1;
            *(uint4*)&Bs[nxt][woff]     = rb0;  *(uint4*)&Bs[nxt][woff + 8] = rb1;
        }
        __syncthreads();
    }

    if constexpr (EPI == 7) {
        // rows of this wave: mbase + wm*64 + mt*16 + g4*4 + r; src = row>>5
        const float inv32 = 1.0f / 32.0f;
        int s0 = mbase >> 5;
        #pragma unroll
        for (int nt = 0; nt < 4; ++nt) {
            int col = nbase + wn*64 + nt*16 + r16;
            float bb = bias[col];
            float p0 = 0.f, p1 = 0.f;
            #pragma unroll
            for (int r = 0; r < 4; ++r) {
                p0 += fsilu(acc[0][nt][r] + bb) + fsilu(acc[1][nt][r] + bb);
                p1 += fsilu(acc[2][nt][r] + bb) + fsilu(acc[3][nt][r] + bb);
            }
            p0 += __shfl_xor(p0, 16); p0 += __shfl_xor(p0, 32);
            p1 += __shfl_xor(p1, 16); p1 += __shfl_xor(p1, 32);
            if (lane < 16) {
                int sA = s0 + wm*2;
                hcat[(size_t)sA*512 + 256 + col]       = (__bf16)(p0 * inv32);
                hcat[(size_t)(sA + 1)*512 + 256 + col] = (__bf16)(p1 * inv32);
            }
        }
    } else {
        #pragma unroll
        for (int mt = 0; mt < 4; ++mt)
            #pragma unroll
            for (int nt = 0; nt < 4; ++nt) {
                int n = nbase + wn*64 + nt*16 + r16;
                #pragma unroll
                for (int r = 0; r < 4; ++r) {
                    int m = mbase + wm*64 + mt*16 + g4*4 + r;
                    float v = acc[mt][nt][r];
                    if (EPI == 0) {
                        if (n < 256) out0[(size_t)m*256 + n] = v + bias[n];
                        else         out1[(size_t)m*256 + (n - 256)] = v;
                    } else if (EPI == 1) {
                        outbf[(size_t)m*ldo + n] = (__bf16)v;
                    } else if (EPI == 2) {
                        outbf[(size_t)m*ldo + n] = (__bf16)fsilu(v + bias[n]);
                    } else if (EPI == 3) {
                        float hv = hmaster[(size_t)m*256 + n] + fsilu(v + bias[n]);
                        hmaster[(size_t)m*256 + n] = hv;
                        hcat[(size_t)m*512 + n] = (__bf16)hv;
                    } else if (EPI == 4) {
                        outbf[(size_t)m*ldo + n] = (__bf16)(v + bias[n]);
                    } else if (EPI == 5) {
                        float hv = v + bias[n];
                        hmaster[(size_t)m*256 + n] = hv;
                        hcat[(size_t)m*512 + n] = (__bf16)hv;
                    } else { // EPI == 6: A-build (m = edge; Sbuf includes b1)
                        int src = m >> 5;
                        int dst = ((m >> 10) << 5) | (m & 31);
                        float sv = out0[(size_t)src*256 + n];
                        float dv = out1[(size_t)dst*256 + n];
                        outbf[(size_t)m*ldo + n] = (__bf16)fsilu(v + sv + dv);
                    }
                }
            }
    }
}

// ---------------- heads ----------------
__global__ void coord_equiv_kernel(const float* __restrict__ h,
                                   const float* __restrict__ coord_w,
                                   const float* __restrict__ G,
                                   const int* __restrict__ invp,
                                   float* __restrict__ out_x) {
    int b = blockIdx.x;
    int tid = threadIdx.x; // 128
    __shared__ float cd[kNN][4];
    if (tid < kNN*3) {
        int nl = tid / 3, j = tid - nl*3;
        const float* hr = h + (size_t)(b*kNN + nl)*kH;
        const float* wr = coord_w + (size_t)j*kH;
        float acc = 0.f;
        #pragma unroll 4
        for (int k = 0; k < kH; ++k) acc += hr[k]*wr[k];
        cd[nl][j] = acc;
    }
    __syncthreads();
    if (tid < kNN*3) {
        int nl = tid / 3, j = tid - nl*3;
        float acc = 0.f;
        for (int g = 0; g < kGS; ++g) {
            int bg = b*kGS + g;
            int p = invp[bg*kNN + nl];
            const float* Gr = G + (size_t)bg*16 + j*4;
            acc += cd[p][0]*Gr[0] + cd[p][1]*Gr[1] + cd[p][2]*Gr[2] + Gr[3];
        }
        out_x[(size_t)(b*kNN + nl)*3 + j] = acc * (1.0f/kGS);
    }
}

__global__ void graphfeat_kernel(const float* __restrict__ h,
                                 const float* __restrict__ lattice_w,
                                 float* __restrict__ out_lat) {
    int g = blockIdx.x;
    int c = threadIdx.x;
    __shared__ float gf[kH];
    float s = 0.f;
    for (int nl = 0; nl < kNN; ++nl) s += h[(size_t)(g*kNN + nl)*kH + c];
    gf[c] = s * (1.0f/kNN);
    __syncthreads();
    if (c < 6) {
        const float* wr = lattice_w + (size_t)c*kH;
        float acc = 0.f;
        #pragma unroll 4
        for (int k = 0; k < kH; ++k) acc += gf[k]*wr[k];
        out_lat[g*6 + c] = acc;
    }
}

} // namespace

extern "C" void kernel_launch(void* const* d_in, const int* in_sizes, int n_in,
                              void* d_out, int out_size, void* d_ws, size_t ws_size,
                              hipStream_t stream) {
    (void)in_sizes; (void)n_in; (void)out_size; (void)ws_size;
    const float* t         = (const float*)d_in[0];
    const float* atom      = (const float*)d_in[1];
    const float* frac      = (const float*)d_in[2];
    const float* lattices  = (const float*)d_in[3];
    const float* G         = (const float*)d_in[4];
    const float* k_mean    = (const float*)d_in[5];
    const float* k_std     = (const float*)d_in[6];
    const float* k_mask    = (const float*)d_in[7];
    const float* k_bias    = (const float*)d_in[8];
    const float* emb_w     = (const float*)d_in[9];
    const float* emb_b     = (const float*)d_in[10];
    const float* latent_w  = (const float*)d_in[11];
    const float* latent_b  = (const float*)d_in[12];
    const float* edge_w1   = (const float*)d_in[13];
    const float* edge_b1   = (const float*)d_in[14];
    const float* edge_w2   = (const float*)d_in[15];
    const float* edge_b2   = (const float*)d_in[16];
    const float* node_w1   = (const float*)d_in[17];
    const float* node_b1   = (const float*)d_in[18];
    const float* node_w2   = (const float*)d_in[19];
    const float* node_b2   = (const float*)d_in[20];
    const float* coord_w   = (const float*)d_in[21];
    const float* lattice_w = (const float*)d_in[22];
    const int*   invp      = (const int*)d_in[25];

    float* out_x   = (float*)d_out;            // [4096,3]
    float* out_lat = (float*)d_out + kN*3;     // [128,6]

    char* base = (char*)d_ws;
    size_t off = 0;
    auto carve = [&](size_t bytes) { char* p = base + off; off += bytes; return p; };
    float*  ltl    = (float*)carve(8192);
    float*  h      = (float*)carve(4194304);          // [4096][256] fp32
    float*  Sbuf   = (float*)carve(4194304);          // S + b1
    float*  Dbuf   = (float*)carve(4194304);
    __bf16* hcat   = (__bf16*)carve(4194304);         // [4096][512] bf16: [h | agg]
    __bf16* t1     = (__bf16*)carve(2097152);         // [4096][256] bf16
    __bf16* fb     = (__bf16*)carve(25165824);        // feats bf16 [131072][96]
    __bf16* Aef    = (__bf16*)carve(67108864);        // [131072][256] bf16 edge activations
    __bf16* w1ab   = (__bf16*)carve(1048576);         // [L][512][256]
    __bf16* w1c    = (__bf16*)carve(262144);          // [L][256][96]
    __bf16* w2b    = (__bf16*)carve(524288);          // [L][256][256]
    __bf16* nw1b   = (__bf16*)carve(1048576);         // [L][256][512]
    __bf16* nw2b   = (__bf16*)carve(524288);          // [L][256][256]
    __bf16* at_bf  = (__bf16*)carve(1048576);         // [4096][128] atom bf16 padded
    __bf16* embwb  = (__bf16*)carve(65536);           // [256][128]
    __bf16* latwb  = (__bf16*)carve(196608);          // [256][384]
    __bf16* tecat  = (__bf16*)carve(3145728);         // [4096][384]: [h0 | temb]

    lattice_kernel<<<1, 128, 0, stream>>>(lattices, k_mean, k_std, k_mask, k_bias, ltl);
    feats_bf_kernel<<<kE/256, 256, 0, stream>>>(frac, lattices, ltl, fb);
    conv_w1ab<<<(4*512*256)/256, 256, 0, stream>>>(edge_w1, w1ab);
    conv_w1c<<<(4*256*kKF)/256, 256, 0, stream>>>(edge_w1, w1c);
    conv_f2b<<<(4*256*256)/256, 256, 0, stream>>>(edge_w2, w2b, 4*256*256);
    conv_f2b<<<(4*256*512)/256, 256, 0, stream>>>(node_w1, nw1b, 4*256*512);
    conv_f2b<<<(4*256*256)/256, 256, 0, stream>>>(node_w2, nw2b, 4*256*256);
    conv_atom<<<(kN*128)/256, 256, 0, stream>>>(atom, at_bf);
    conv_embw<<<(256*128)/256, 256, 0, stream>>>(emb_w, embwb);
    conv_f2b<<<(256*384)/256, 256, 0, stream>>>(latent_w, latwb, 256*384);
    temb_kernel<<<kB, 128, 0, stream>>>(t, tecat);

    // embed GEMM1: h0 = at_bf[4096,128] @ embwb[256,128]^T + emb_b -> tecat[:, :256]
    gemm_bf16<128, 4><<<dim3(32, 2), 256, 0, stream>>>(
        at_bf, 128, embwb, 128, emb_b,
        nullptr, nullptr, tecat, 384, nullptr, nullptr);
    // embed GEMM2: h = tecat[4096,384] @ latwb[256,384]^T + latent_b -> h fp32 + hcat bf16
    gemm_bf16<384, 5><<<dim3(32, 2), 256, 0, stream>>>(
        tecat, 384, latwb, 384, latent_b,
        nullptr, nullptr, nullptr, 0, h, hcat);

    for (int l = 0; l < kL; ++l) {
        // S/D: [4096,256(of 512)] @ w1ab[512][256]^T; Sbuf includes +b1
        gemm_bf16<256, 0><<<dim3(32, 4), 256, 0, stream>>>(
            hcat, 512, w1ab + (size_t)l*512*256, 256,
            edge_b1 + l*256, Sbuf, Dbuf, nullptr, 0, nullptr, nullptr);
        // Fproj + A-build: Aef[e][n] = silu(fb@w1c^T + S[src] + D[dst])
        gemm_bf16<96, 6><<<dim3(1024, 2), 256, 0, stream>>>(
            fb, kKF, w1c + (size_t)l*256*kKF, kKF,
            nullptr, Sbuf, Dbuf, Aef, 256, nullptr, nullptr);
        // edge GEMM2 + scatter-mean agg -> hcat[:, 256:512]
        gemm_bf16<256, 7><<<dim3(1024, 2), 256, 0, stream>>>(
            Aef, 256, w2b + (size_t)l*256*256, 256,
            edge_b2 + l*256, nullptr, nullptr, nullptr, 0, nullptr, hcat);
        // node MLP
        gemm_bf16<512, 2><<<dim3(32, 2), 256, 0, stream>>>(
            hcat, 512, nw1b + (size_t)l*256*512, 512,
            node_b1 + l*256, nullptr, nullptr, t1, 256, nullptr, nullptr);
        gemm_bf16<256, 3><<<dim3(32, 2), 256, 0, stream>>>(
            t1, 256, nw2b + (size_t)l*256*256, 256,
            node_b2 + l*256, nullptr, nullptr, nullptr, 0, h, hcat);
    }
    coord_equiv_kernel<<<kB, 128, 0, stream>>>(h, coord_w, G, invp, out_x);
    graphfeat_kernel<<<kB, 256, 0, stream>>>(h, lattice_w, out_lat);
}